// Round 16
// baseline (148.246 us; speedup 1.0000x reference)
//
#include <hip/hip_runtime.h>
#include <hip/hip_bf16.h>
#include <math.h>

#define BB    2
#define NN    2048
#define HSZ   1024
#define NH    16
#define HD    64
#define SEGW  20

#define LOG2E  1.4426950408889634f
#define QSCALE (0.125f * LOG2E)     // folded into Q at projection time
#define DTHR   8.0f                 // defer-max threshold (log2 units)

typedef unsigned short u16;
typedef unsigned int   u32;
using bf16x8 = __attribute__((ext_vector_type(8))) short;
using f32x4  = __attribute__((ext_vector_type(4))) float;
using f32x16 = __attribute__((ext_vector_type(16))) float;

// float -> bf16 (RNE), manual
__device__ __forceinline__ u16 f2b(float f) {
    union { float f; u32 u; } x; x.f = f;
    u32 r = x.u + 0x7FFF + ((x.u >> 16) & 1);
    return (u16)(r >> 16);
}
// float -> bf16 via compiler cvt (hot path)
__device__ __forceinline__ u16 f2bc(float f) {
    __hip_bfloat16 h = __float2bfloat16(f);
    return *reinterpret_cast<u16*>(&h);
}
// packed 2x f32 -> bf16x2 in one instruction (lo -> low half)
__device__ __forceinline__ u32 cvtpk(float lo, float hi) {
    u32 r;
    asm("v_cvt_pk_bf16_f32 %0, %1, %2" : "=v"(r) : "v"(lo), "v"(hi));
    return r;
}
// 3-input max, single instruction
__device__ __forceinline__ float max3(float a, float b, float c) {
    float d;
    asm("v_max3_f32 %0, %1, %2, %3" : "=v"(d) : "v"(a), "v"(b), "v"(c));
    return d;
}

// async global->LDS, 16B/lane; lds base wave-uniform
__device__ __forceinline__ void gload16(void* lds, const void* g) {
    __builtin_amdgcn_global_load_lds(
        (const __attribute__((address_space(1))) void*)g,
        (__attribute__((address_space(3))) void*)lds, 16, 0, 0);
}

// v_permlane32_swap_b32: a.row1 <-> b.row0  (rows = 32-lane halves)
__device__ __forceinline__ void pswap(u32& a, u32& b) {
    asm volatile("v_permlane32_swap_b32 %0, %1" : "+v"(a), "+v"(b));
}

// ---------------------------------------------------------------------------
__global__ __launch_bounds__(256)
void cast_k(const float* __restrict__ hs, const float* __restrict__ Wq,
            const float* __restrict__ Wk, const float* __restrict__ Wv,
            const float* __restrict__ Wp, u16* __restrict__ hsb,
            u16* __restrict__ wqb, u16* __restrict__ wkb,
            u16* __restrict__ wvb, u16* __restrict__ wpb) {
    size_t idx = ((size_t)blockIdx.x * 256 + threadIdx.x) * 4;
    const float* s; u16* d; size_t o;
    const size_t HSN = 4194304, WN = 1048576;
    if      (idx < HSN)          { s = hs; d = hsb; o = idx; }
    else if (idx < HSN + WN)     { s = Wq; d = wqb; o = idx - HSN; }
    else if (idx < HSN + 2*WN)   { s = Wk; d = wkb; o = idx - HSN - WN; }
    else if (idx < HSN + 3*WN)   { s = Wv; d = wvb; o = idx - HSN - 2*WN; }
    else                         { s = Wp; d = wpb; o = idx - HSN - 3*WN; }
    float4 v = *(const float4*)(s + o);
    u32 lo = f2b(v.x) | ((u32)f2b(v.y) << 16);
    u32 hi = f2b(v.z) | ((u32)f2b(v.w) << 16);
    *(uint2*)(d + o) = uint2{lo, hi};
}

// ---------------------------------------------------------------------------
__global__ void rope_table_k(float* __restrict__ tab) {
    int n = blockIdx.x, d = threadIdx.x;
    float c = 1.f, s = 0.f;
    if (d < 3 * SEGW) {
        int seg = d / SEGW;
        int jj  = (d % SEGW) % (SEGW / 2);
        int rem = n & 255;
        int pos = (seg == 0) ? (n >> 8) : ((seg == 1) ? (rem >> 4) : (rem & 15));
        float omega = powf(10000.f, -(float)jj / 10.f);
        float fr = (float)pos * omega;
        s = sinf(fr); c = cosf(fr);
    }
    tab[(n * 64 + d) * 2 + 0] = c;
    tab[(n * 64 + d) * 2 + 1] = s;
}

// ---------------------------------------------------------------------------
// Fused QKV GEMM: ONE block computes q,k,v for its (m-panel 128, o-tile 64),
// staging the shared A tile ONCE per k-step + 3 B tiles (Wq/Wk/Wv).
// LDS traffic per FLOP -20%, A staging -33% vs 3 separate launches.
// BK=32, dbuf, 1 barrier/iter, (c&3)^(row&3) source pre-swizzle,
// XCD remap: flat = bx + by*16; o0=(flat>>5)*64; m0=(flat&31)*128
// -> blocks sharing an A-panel land on one XCD (ids == m mod 32).
// ---------------------------------------------------------------------------
__global__ __launch_bounds__(256)
void qkv3_k(const u16* __restrict__ X,
            const u16* __restrict__ Wq, const u16* __restrict__ Wk, const u16* __restrict__ Wv,
            const float* __restrict__ bq, const float* __restrict__ bk, const float* __restrict__ bv,
            u16* __restrict__ qo, u16* __restrict__ ko, u16* __restrict__ vo,
            const float* __restrict__ tab) {
    __shared__ u16 As[2][128 * 32];      // 16KB
    __shared__ u16 Bs[2][3][64 * 32];    // 24KB

    const int t  = threadIdx.x;
    const int w  = t >> 6;
    const int l  = t & 63;
    const int flat = blockIdx.x + (blockIdx.y << 4);
    const int o0 = (flat >> 5) * 64;     // 16 o-tiles
    const int m0 = (flat & 31) * 128;    // 32 m-panels
    const int wr = (w >> 1) * 64;
    const int wc = (w & 1) * 32;

    const int ch  = (w << 6) + l;        // 0..255
    const int rA0 = ch >> 2,         cA0 = (((ch & 3) ^ (rA0 & 3))) * 8;
    const int rA1 = (ch + 256) >> 2, cA1 = (((ch & 3) ^ (rA1 & 3))) * 8;
    const int rB  = ch >> 2,         cB  = (((ch & 3) ^ (rB & 3))) * 8;
    const int kbyte = (((l >> 4) ^ (l & 3)) << 4);

    const u16* Wptr[3] = {Wq, Wk, Wv};

    f32x4 acc[3][4][2] = {};

    // prologue: stage k0=0 into buf 0
    gload16(As[0] + ((w << 6)) * 8,       X + (size_t)(m0 + rA0) * HSZ + cA0);
    gload16(As[0] + (256 + (w << 6)) * 8, X + (size_t)(m0 + rA1) * HSZ + cA1);
#pragma unroll
    for (int p = 0; p < 3; ++p)
        gload16(Bs[0][p] + ((w << 6)) * 8, Wptr[p] + (size_t)(o0 + rB) * HSZ + cB);
    __syncthreads();

    int cur = 0;
    for (int k0 = 0; k0 < HSZ; k0 += 32, cur ^= 1) {
        if (k0 + 32 < HSZ) {
            int kn = k0 + 32;
            gload16(As[cur ^ 1] + ((w << 6)) * 8,       X + (size_t)(m0 + rA0) * HSZ + kn + cA0);
            gload16(As[cur ^ 1] + (256 + (w << 6)) * 8, X + (size_t)(m0 + rA1) * HSZ + kn + cA1);
#pragma unroll
            for (int p = 0; p < 3; ++p)
                gload16(Bs[cur ^ 1][p] + ((w << 6)) * 8, Wptr[p] + (size_t)(o0 + rB) * HSZ + kn + cB);
        }
        bf16x8 af[4];
#pragma unroll
        for (int i = 0; i < 4; ++i) {
            int row = wr + i * 16 + (l & 15);
            af[i] = *(const bf16x8*)((const char*)As[cur] + row * 64 + kbyte);
        }
        __builtin_amdgcn_s_setprio(1);
#pragma unroll
        for (int p = 0; p < 3; ++p) {
            bf16x8 bfr[2];
#pragma unroll
            for (int j = 0; j < 2; ++j) {
                int row = wc + j * 16 + (l & 15);
                bfr[j] = *(const bf16x8*)((const char*)Bs[cur][p] + row * 64 + kbyte);
            }
#pragma unroll
            for (int i = 0; i < 4; ++i)
#pragma unroll
                for (int j = 0; j < 2; ++j)
                    acc[p][i][j] = __builtin_amdgcn_mfma_f32_16x16x32_bf16(af[i], bfr[j], acc[p][i][j], 0, 0, 0);
        }
        __builtin_amdgcn_s_setprio(0);
        __syncthreads();
    }

    // ---- epilogues: p=0 q (rope+QSCALE), p=1 k (rope), p=2 v (transposed) ----
    const int h = o0 >> 6;               // 64-wide o-tile == one head
#pragma unroll
    for (int p = 0; p < 3; ++p) {
        const float* bias = (p == 0) ? bq : (p == 1) ? bk : bv;
        u16* out = (p == 0) ? qo : (p == 1) ? ko : vo;
#pragma unroll
        for (int j = 0; j < 2; ++j) {
            int oc = o0 + wc + j * 16 + (l & 15);
            int d  = oc & 63;
            float bvv = bias[oc];
            if (p == 2) {
#pragma unroll
                for (int rt = 0; rt < 4; ++rt) {
                    int base = m0 + wr + rt * 16 + (l >> 4) * 4;
                    int b_ = base >> 11, n0 = base & (NN - 1);
                    u16 e[4];
#pragma unroll
                    for (int r = 0; r < 4; ++r) e[r] = f2b(acc[p][rt][j][r] + bvv);
                    u32 lo = e[0] | ((u32)e[1] << 16);
                    u32 hi = e[2] | ((u32)e[3] << 16);
                    u16* vp = out + (((size_t)b_ * NH + h) * HD + d) * NN + n0;
                    *(uint2*)vp = uint2{lo, hi};
                }
            } else {
                float scl = (p == 0) ? QSCALE : 1.f;
#pragma unroll
                for (int rt = 0; rt < 4; ++rt)
#pragma unroll
                    for (int r = 0; r < 4; ++r) {
                        int m = m0 + wr + rt * 16 + (l >> 4) * 4 + r;
                        int n = m & (NN - 1), b_ = m >> 11;
                        float v = acc[p][rt][j][r] + bvv;
                        float2 cs = ((const float2*)tab)[n * 64 + d];
                        float part = __shfl_xor(v, 1);
                        float vr = (l & 1) ? fmaf(part, cs.y, v * cs.x)
                                           : fmaf(-part, cs.y, v * cs.x);
                        u16* qp = out + (((size_t)b_ * NH + h) * NN + n) * HD + d;
                        *qp = f2b(vr * scl);
                    }
            }
        }
    }
}

// ---------------------------------------------------------------------------
// The 140.4-proven GEMM (used for the output projection): BM=BN=128, BK=32,
// A AND B via global_load_lds dbuf (32KB), XCD remap (flat = bx + by*8).
// mode 3: fp32 [m][o] out.
// ---------------------------------------------------------------------------
__device__ __forceinline__
void gemm_body(const u16* __restrict__ X, const u16* __restrict__ Wb,
               const float* __restrict__ bias, void* __restrict__ out,
               const float* __restrict__ tab, int mode) {
    __shared__ u16 As[2][128 * 32];
    __shared__ u16 Bs[2][128 * 32];

    const int t  = threadIdx.x;
    const int w  = t >> 6;
    const int l  = t & 63;
    const int flat = blockIdx.x + (blockIdx.y << 3);
    const int o0 = (flat >> 5) * 128;
    const int m0 = (flat & 31) * 128;
    const int wr = (w >> 1) * 64;
    const int wc = (w & 1) * 64;

    const int ch  = (w << 6) + l;
    const int rA0 = ch >> 2,         cA0 = (((ch & 3) ^ (rA0 & 3))) * 8;
    const int rA1 = (ch + 256) >> 2, cA1 = (((ch & 3) ^ (rA1 & 3))) * 8;
    const int kbyte = (((l >> 4) ^ (l & 3)) << 4);

    f32x4 acc[4][4] = {};

    gload16(As[0] + ((w << 6)) * 8,       X  + (size_t)(m0 + rA0) * HSZ + cA0);
    gload16(As[0] + (256 + (w << 6)) * 8, X  + (size_t)(m0 + rA1) * HSZ + cA1);
    gload16(Bs[0] + ((w << 6)) * 8,       Wb + (size_t)(o0 + rA0) * HSZ + cA0);
    gload16(Bs[0] + (256 + (w << 6)) * 8, Wb + (size_t)(o0 + rA1) * HSZ + cA1);
    __syncthreads();

    int cur = 0;
    for (int k0 = 0; k0 < HSZ; k0 += 32, cur ^= 1) {
        if (k0 + 32 < HSZ) {
            int kn = k0 + 32;
            gload16(As[cur ^ 1] + ((w << 6)) * 8,       X  + (size_t)(m0 + rA0) * HSZ + kn + cA0);
            gload16(As[cur ^ 1] + (256 + (w << 6)) * 8, X  + (size_t)(m0 + rA1) * HSZ + kn + cA1);
            gload16(Bs[cur ^ 1] + ((w << 6)) * 8,       Wb + (size_t)(o0 + rA0) * HSZ + kn + cA0);
            gload16(Bs[cur ^ 1] + (256 + (w << 6)) * 8, Wb + (size_t)(o0 + rA1) * HSZ + kn + cA1);
        }
        bf16x8 af[4], bfr[4];
#pragma unroll
        for (int i = 0; i < 4; ++i) {
            int row = wr + i * 16 + (l & 15);
            af[i] = *(const bf16x8*)((const char*)As[cur] + row * 64 + kbyte);
        }
#pragma unroll
        for (int j = 0; j < 4; ++j) {
            int row = wc + j * 16 + (l & 15);
            bfr[j] = *(const bf16x8*)((const char*)Bs[cur] + row * 64 + kbyte);
        }
        __builtin_amdgcn_s_setprio(1);
#pragma unroll
        for (int i = 0; i < 4; ++i)
#pragma unroll
            for (int j = 0; j < 4; ++j)
                acc[i][j] = __builtin_amdgcn_mfma_f32_16x16x32_bf16(af[i], bfr[j], acc[i][j], 0, 0, 0);
        __builtin_amdgcn_s_setprio(0);
        __syncthreads();
    }

#pragma unroll
    for (int j = 0; j < 4; ++j) {
        int oc = o0 + wc + j * 16 + (l & 15);
        float bv = bias[oc];
        if (mode == 3) {
#pragma unroll
            for (int rt = 0; rt < 4; ++rt)
#pragma unroll
                for (int r = 0; r < 4; ++r) {
                    int m = m0 + wr + rt * 16 + (l >> 4) * 4 + r;
                    ((float*)out)[(size_t)m * HSZ + oc] = acc[rt][j][r] + bv;
                }
        }
    }
    (void)tab;
}

__global__ __launch_bounds__(256)
void projo_k(const u16* __restrict__ X, const u16* __restrict__ W,
             const float* __restrict__ b, float* __restrict__ out) {
    gemm_body(X, W, b, out, nullptr, 3);
}

// ---------------------------------------------------------------------------
// Swapped-QK^T flash attention (proven structure) with VALU diet:
//  - P pack via v_cvt_pk_bf16_f32; row-max via v_max3_f32 tree;
//  - l-sum via ones-MFMA (all lacc rows equal -> l = lacc[0], no shfl).
// KVBLK=64, QBLK=128, K/V dbuf 32KB, P in-register via permlane32_swap.
// ---------------------------------------------------------------------------
__global__ __launch_bounds__(256)
void attn_mfma_k(const u16* __restrict__ Qb, const u16* __restrict__ Kb,
                 const u16* __restrict__ Vtb, u16* __restrict__ ctxb) {
    __shared__ u16 KVs[2][2][64 * 64];   // [buf][0=K [kv][d], 1=V^T [d][kv]]

    const int t = threadIdx.x, w = t >> 6, l = t & 63;
    const int h = l >> 5;                // 32-lane half
    int f  = blockIdx.y * 16 + blockIdx.x;
    int bh = (f & 7) * 4 + ((f >> 3) & 3);   // 4 heads per XCD -> K/V L2-resident
    int qt = f >> 5;
    const int b_ = bh >> 4, hd = bh & 15;

    const u16* Qg = Qb + ((size_t)bh * NN + qt * 128) * HD;
    const u16* Kg = Kb + (size_t)bh * NN * HD;
    const u16* Vg = Vtb + (size_t)bh * HD * NN;

    const int xr   = (l & 7) << 4;
    const int h16  = h * 16;
    const int rowo = (l & 31) * 128;
    int kb4[4];
#pragma unroll
    for (int ks = 0; ks < 4; ++ks) kb4[ks] = ((ks * 32) | h16) ^ xr;

    const int ch  = w * 64 + l;
    const int r0  = ch >> 3,          sl0 = (ch & 7) ^ (r0 & 7);
    const int r1  = (ch + 256) >> 3,  sl1 = (ch & 7) ^ (r1 & 7);

    // ---- stage Q (16KB over KVs[0]) and hoist B-frags ----
#pragma unroll
    for (int s = 0; s < 4; ++s) {
        int c = s * 256 + ch;
        int row = c >> 3, sl = (c & 7) ^ (row & 7);
        gload16(&KVs[0][0][0] + (s * 256 + w * 64) * 8, Qg + row * HD + sl * 8);
    }
    __syncthreads();
    bf16x8 qf[4];
    {
        const char* Ql = (const char*)&KVs[0][0][0];
        int qrow = (w * 32 + (l & 31)) * 128;
#pragma unroll
        for (int ks = 0; ks < 4; ++ks)
            qf[ks] = *(const bf16x8*)(Ql + qrow + kb4[ks]);
    }
    __syncthreads();                     // all Q reads done before overwrite

    // ---- stage K/V tile 0 ----
    gload16(&KVs[0][0][0] + (w * 64) * 8,        Kg + (size_t)r0 * HD + sl0 * 8);
    gload16(&KVs[0][0][0] + (256 + w * 64) * 8,  Kg + (size_t)r1 * HD + sl1 * 8);
    gload16(&KVs[0][1][0] + (w * 64) * 8,        Vg + (size_t)r0 * NN + sl0 * 8);
    gload16(&KVs[0][1][0] + (256 + w * 64) * 8,  Vg + (size_t)r1 * NN + sl1 * 8);
    __syncthreads();

    bf16x8 ones;
#pragma unroll
    for (int i = 0; i < 8; ++i) ones[i] = (short)0x3F80;   // bf16 1.0

    float m_i = -INFINITY;
    f32x16 oa0 = {}, oa1 = {}, lacc = {};

    int cur = 0;
    for (int kt = 0; kt < NN / 64; ++kt, cur ^= 1) {
        if (kt + 1 < NN / 64) {          // prefetch next tile (drained at barrier)
            int nx = (kt + 1) * 64;
            gload16(&KVs[cur ^ 1][0][0] + (w * 64) * 8,       Kg + (size_t)(nx + r0) * HD + sl0 * 8);
            gload16(&KVs[cur ^ 1][0][0] + (256 + w * 64) * 8, Kg + (size_t)(nx + r1) * HD + sl1 * 8);
            gload16(&KVs[cur ^ 1][1][0] + (w * 64) * 8,       Vg + (size_t)r0 * NN + nx + sl0 * 8);
            gload16(&KVs[cur ^ 1][1][0] + (256 + w * 64) * 8, Vg + (size_t)r1 * NN + nx + sl1 * 8);
        }

        // ---- S^T = K Q^T : lane holds q=l&31, kv rows per reg ----
        const char* Kl = (const char*)&KVs[cur][0][0];
        f32x16 sa0 = {}, sa1 = {};
        __builtin_amdgcn_s_setprio(1);
#pragma unroll
        for (int ks = 0; ks < 4; ++ks) {
            bf16x8 k0 = *(const bf16x8*)(Kl + rowo + kb4[ks]);
            bf16x8 k1 = *(const bf16x8*)(Kl + 4096 + rowo + kb4[ks]);
            sa0 = __builtin_amdgcn_mfma_f32_32x32x16_bf16(k0, qf[ks], sa0, 0, 0, 0);
            sa1 = __builtin_amdgcn_mfma_f32_32x32x16_bf16(k1, qf[ks], sa1, 0, 0, 0);
        }
        __builtin_amdgcn_s_setprio(0);

        // ---- lane-local lazy max (v_max3 tree over 32 values) ----
        float a0 = max3(sa0[0], sa0[1], sa0[2]);
        float a1 = max3(sa0[3], sa0[4], sa0[5]);
        float a2 = max3(sa0[6], sa0[7], sa0[8]);
        float a3 = max3(sa0[9], sa0[10], sa0[11]);
        float a4 = max3(sa0[12], sa0[13], sa0[14]);
        float a5 = max3(sa1[0], sa1[1], sa1[2]);
        float a6 = max3(sa1[3], sa1[4], sa1[5]);
        float a7 = max3(sa1[6], sa1[7], sa1[8]);
        float a8 = max3(sa1[9], sa1[10], sa1[11]);
        float a9 = max3(sa1[12], sa1[13], sa1[14]);
        float aa = fmaxf(sa0[15], sa1[15]);
        float b0 = max3(a0, a1, a2);
        float b1 = max3(a3, a4, a5);
        float b2 = max3(a6, a7, a8);
        float b3 = max3(a9, aa, b0);
        float pmv = max3(b1, b2, b3);
        if (__any(pmv > m_i + DTHR)) {   // tile 0, then rare
            float mx = fmaxf(pmv, __shfl_xor(pmv, 32));
            float mn = fmaxf(m_i, mx);
            float alpha = __builtin_amdgcn_exp2f(m_i - mn);
            m_i = mn;
#pragma unroll
            for (int r = 0; r < 16; ++r) {
                oa0[r] *= alpha; oa1[r] *= alpha; lacc[r] *= alpha;
            }
        }

        // ---- P = exp2(S - m), packed cvt to bf16 pairs in-register ----
        u32 o_[16];
#pragma unroll
        for (int j = 0; j < 8; ++j) {
            float pa = __builtin_amdgcn_exp2f(sa0[2 * j]     - m_i);
            float pb = __builtin_amdgcn_exp2f(sa0[2 * j + 1] - m_i);
            float pc = __builtin_amdgcn_exp2f(sa1[2 * j]     - m_i);
            float pd = __builtin_amdgcn_exp2f(sa1[2 * j + 1] - m_i);
            o_[j]     = cvtpk(pa, pb);
            o_[8 + j] = cvtpk(pc, pd);
        }

        // ---- redistribute halves ----
        pswap(o_[0], o_[2]);   pswap(o_[1], o_[3]);
        pswap(o_[4], o_[6]);   pswap(o_[5], o_[7]);
        pswap(o_[8], o_[10]);  pswap(o_[9], o_[11]);
        pswap(o_[12], o_[14]); pswap(o_[13], o_[15]);

        // ---- O^T += V^T P^T ; l += 1^T P^T (ones-MFMA row sums) ----
        const char* Vl = (const char*)&KVs[cur][1][0];
        __builtin_amdgcn_s_setprio(1);
#pragma unroll
        for (int ks2 = 0; ks2 < 4; ++ks2) {
            union { u32 u[4]; bf16x8 v; } fr;
            fr.u[0] = o_[4 * ks2 + 0]; fr.u[1] = o_[4 * ks2 + 1];
            fr.u[2] = o_[4 * ks2 + 2]; fr.u[3] = o_[4 * ks2 + 3];
            bf16x8 v0 = *(const bf16x8*)(Vl + rowo + kb4[ks2]);
            bf16x8 v1 = *(const bf16x8*)(Vl + 4096 + rowo + kb4[ks2]);
            lacc = __builtin_amdgcn_mfma_f32_32x32x16_bf16(ones, fr.v, lacc, 0, 0, 0);
            oa0 = __builtin_amdgcn_mfma_f32_32x32x16_bf16(v0, fr.v, oa0, 0, 0, 0);
            oa1 = __builtin_amdgcn_mfma_f32_32x32x16_bf16(v1, fr.v, oa1, 0, 0, 0);
        }
        __builtin_amdgcn_s_setprio(0);

        __syncthreads();     // readers done with cur; prefetch (cur^1) drained
    }

    // ---- finalize: every lacc row equals l for this lane's q-col ----
    float inv = 1.f / lacc[0];
    int n = qt * 128 + w * 32 + (l & 31);
    u16* op = ctxb + ((size_t)b_ * NN + n) * HSZ + hd * 64;
#pragma unroll
    for (int dt = 0; dt < 2; ++dt) {
        const f32x16& oa = dt ? oa1 : oa0;
#pragma unroll
        for (int rg = 0; rg < 4; ++rg) {
            int d0 = 4 * h + 8 * rg + 32 * dt;
            u16 e0 = f2bc(oa[4 * rg + 0] * inv);
            u16 e1 = f2bc(oa[4 * rg + 1] * inv);
            u16 e2 = f2bc(oa[4 * rg + 2] * inv);
            u16 e3 = f2bc(oa[4 * rg + 3] * inv);
            *(uint2*)(op + d0) = uint2{e0 | ((u32)e1 << 16), e2 | ((u32)e3 << 16)};
        }
    }
}

// ---------------------------------------------------------------------------
extern "C" void kernel_launch(void* const* d_in, const int* in_sizes, int n_in,
                              void* d_out, int out_size, void* d_ws, size_t ws_size,
                              hipStream_t stream) {
    (void)in_sizes; (void)n_in; (void)out_size; (void)ws_size;
    const float* hs = (const float*)d_in[0];
    const float* Wq = (const float*)d_in[1];
    const float* bq = (const float*)d_in[2];
    const float* Wk = (const float*)d_in[3];
    const float* bk = (const float*)d_in[4];
    const float* Wv = (const float*)d_in[5];
    const float* bv = (const float*)d_in[6];
    const float* Wp = (const float*)d_in[7];
    const float* bp = (const float*)d_in[8];

    char* ws = (char*)d_ws;
    u16*   hsb  = (u16*)(ws);
    u16*   Wqb  = (u16*)(ws + 8388608);
    u16*   Wkb  = (u16*)(ws + 10485760);
    u16*   Wvb  = (u16*)(ws + 12582912);
    u16*   Wpb  = (u16*)(ws + 14680064);
    u16*   qb   = (u16*)(ws + 16777216);
    u16*   kb   = (u16*)(ws + 25165824);
    u16*   vtb  = (u16*)(ws + 33554432);
    u16*   ctxb = (u16*)(ws + 41943040);
    float* tab  = (float*)(ws + 50331648);

    cast_k<<<8192, 256, 0, stream>>>(hs, Wq, Wk, Wv, Wp, hsb, Wqb, Wkb, Wvb, Wpb);
    rope_table_k<<<NN, 64, 0, stream>>>(tab);

    qkv3_k<<<dim3(16, 32), 256, 0, stream>>>(
        hsb, Wqb, Wkb, Wvb, bq, bk, bv, qb, kb, vtb, tab);

    attn_mfma_k<<<dim3(NN / 128, BB * NH), 256, 0, stream>>>(qb, kb, vtb, ctxb);

    projo_k<<<dim3(HSZ / 128, (BB * NN) / 128), 256, 0, stream>>>(ctxb, Wpb, bp, (float*)d_out);
}

// Round 17
// 133.303 us; speedup vs baseline: 1.1121x; 1.1121x over previous
//
#include <hip/hip_runtime.h>
#include <hip/hip_bf16.h>
#include <math.h>

#define BB    2
#define NN    2048
#define HSZ   1024
#define NH    16
#define HD    64
#define SEGW  20

#define LOG2E  1.4426950408889634f
#define QSCALE (0.125f * LOG2E)     // folded into Q at projection time
#define DTHR   8.0f                 // defer-max threshold (log2 units)

typedef unsigned short u16;
typedef unsigned int   u32;
using bf16x8 = __attribute__((ext_vector_type(8))) short;
using f32x4  = __attribute__((ext_vector_type(4))) float;
using f32x16 = __attribute__((ext_vector_type(16))) float;

// float -> bf16 (RNE), manual
__device__ __forceinline__ u16 f2b(float f) {
    union { float f; u32 u; } x; x.f = f;
    u32 r = x.u + 0x7FFF + ((x.u >> 16) & 1);
    return (u16)(r >> 16);
}
// float -> bf16 via compiler cvt (hot path)
__device__ __forceinline__ u16 f2bc(float f) {
    __hip_bfloat16 h = __float2bfloat16(f);
    return *reinterpret_cast<u16*>(&h);
}
// packed 2x f32 -> bf16x2 in one instruction (lo -> low half)
__device__ __forceinline__ u32 cvtpk(float lo, float hi) {
    u32 r;
    asm("v_cvt_pk_bf16_f32 %0, %1, %2" : "=v"(r) : "v"(lo), "v"(hi));
    return r;
}
// 3-input max, single instruction
__device__ __forceinline__ float max3(float a, float b, float c) {
    float d;
    asm("v_max3_f32 %0, %1, %2, %3" : "=v"(d) : "v"(a), "v"(b), "v"(c));
    return d;
}

// async global->LDS, 16B/lane; lds base wave-uniform
__device__ __forceinline__ void gload16(void* lds, const void* g) {
    __builtin_amdgcn_global_load_lds(
        (const __attribute__((address_space(1))) void*)g,
        (__attribute__((address_space(3))) void*)lds, 16, 0, 0);
}

// v_permlane32_swap_b32: a.row1 <-> b.row0  (rows = 32-lane halves)
__device__ __forceinline__ void pswap(u32& a, u32& b) {
    asm volatile("v_permlane32_swap_b32 %0, %1" : "+v"(a), "+v"(b));
}

// ---------------------------------------------------------------------------
__global__ __launch_bounds__(256)
void cast_k(const float* __restrict__ hs, const float* __restrict__ Wq,
            const float* __restrict__ Wk, const float* __restrict__ Wv,
            const float* __restrict__ Wp, u16* __restrict__ hsb,
            u16* __restrict__ wqb, u16* __restrict__ wkb,
            u16* __restrict__ wvb, u16* __restrict__ wpb) {
    size_t idx = ((size_t)blockIdx.x * 256 + threadIdx.x) * 4;
    const float* s; u16* d; size_t o;
    const size_t HSN = 4194304, WN = 1048576;
    if      (idx < HSN)          { s = hs; d = hsb; o = idx; }
    else if (idx < HSN + WN)     { s = Wq; d = wqb; o = idx - HSN; }
    else if (idx < HSN + 2*WN)   { s = Wk; d = wkb; o = idx - HSN - WN; }
    else if (idx < HSN + 3*WN)   { s = Wv; d = wvb; o = idx - HSN - 2*WN; }
    else                         { s = Wp; d = wpb; o = idx - HSN - 3*WN; }
    float4 v = *(const float4*)(s + o);
    u32 lo = f2b(v.x) | ((u32)f2b(v.y) << 16);
    u32 hi = f2b(v.z) | ((u32)f2b(v.w) << 16);
    *(uint2*)(d + o) = uint2{lo, hi};
}

// ---------------------------------------------------------------------------
__global__ void rope_table_k(float* __restrict__ tab) {
    int n = blockIdx.x, d = threadIdx.x;
    float c = 1.f, s = 0.f;
    if (d < 3 * SEGW) {
        int seg = d / SEGW;
        int jj  = (d % SEGW) % (SEGW / 2);
        int rem = n & 255;
        int pos = (seg == 0) ? (n >> 8) : ((seg == 1) ? (rem >> 4) : (rem & 15));
        float omega = powf(10000.f, -(float)jj / 10.f);
        float fr = (float)pos * omega;
        s = sinf(fr); c = cosf(fr);
    }
    tab[(n * 64 + d) * 2 + 0] = c;
    tab[(n * 64 + d) * 2 + 1] = s;
}

// ---------------------------------------------------------------------------
// The proven GEMM: BM=BN=128, BK=32, A AND B both via global_load_lds
// dbuf (32KB LDS), 1 barrier/iter, staging source pre-swizzled by
// (c&3)^(row&3), XCD-locality remap (flat = bx + by*8).
// mode 0: rope+QSCALE bf16 [bh][n][d]; 1: rope bf16; 2: bf16 [bh][d][n] (V^T);
// mode 3: fp32 [m][o].
// ---------------------------------------------------------------------------
__device__ __forceinline__
void gemm_body(const u16* __restrict__ X, const u16* __restrict__ Wb,
               const float* __restrict__ bias, void* __restrict__ out,
               const float* __restrict__ tab, int mode) {
    __shared__ u16 As[2][128 * 32];
    __shared__ u16 Bs[2][128 * 32];

    const int t  = threadIdx.x;
    const int w  = t >> 6;
    const int l  = t & 63;
    const int flat = blockIdx.x + (blockIdx.y << 3);
    const int o0 = (flat >> 5) * 128;
    const int m0 = (flat & 31) * 128;
    const int wr = (w >> 1) * 64;
    const int wc = (w & 1) * 64;

    const int ch  = (w << 6) + l;
    const int rA0 = ch >> 2,         cA0 = (((ch & 3) ^ (rA0 & 3))) * 8;
    const int rA1 = (ch + 256) >> 2, cA1 = (((ch & 3) ^ (rA1 & 3))) * 8;
    const int kbyte = (((l >> 4) ^ (l & 3)) << 4);

    f32x4 acc[4][4] = {};

    gload16(As[0] + ((w << 6)) * 8,       X  + (size_t)(m0 + rA0) * HSZ + cA0);
    gload16(As[0] + (256 + (w << 6)) * 8, X  + (size_t)(m0 + rA1) * HSZ + cA1);
    gload16(Bs[0] + ((w << 6)) * 8,       Wb + (size_t)(o0 + rA0) * HSZ + cA0);
    gload16(Bs[0] + (256 + (w << 6)) * 8, Wb + (size_t)(o0 + rA1) * HSZ + cA1);
    __syncthreads();

    int cur = 0;
    for (int k0 = 0; k0 < HSZ; k0 += 32, cur ^= 1) {
        if (k0 + 32 < HSZ) {
            int kn = k0 + 32;
            gload16(As[cur ^ 1] + ((w << 6)) * 8,       X  + (size_t)(m0 + rA0) * HSZ + kn + cA0);
            gload16(As[cur ^ 1] + (256 + (w << 6)) * 8, X  + (size_t)(m0 + rA1) * HSZ + kn + cA1);
            gload16(Bs[cur ^ 1] + ((w << 6)) * 8,       Wb + (size_t)(o0 + rA0) * HSZ + kn + cA0);
            gload16(Bs[cur ^ 1] + (256 + (w << 6)) * 8, Wb + (size_t)(o0 + rA1) * HSZ + kn + cA1);
        }
        bf16x8 af[4], bfr[4];
#pragma unroll
        for (int i = 0; i < 4; ++i) {
            int row = wr + i * 16 + (l & 15);
            af[i] = *(const bf16x8*)((const char*)As[cur] + row * 64 + kbyte);
        }
#pragma unroll
        for (int j = 0; j < 4; ++j) {
            int row = wc + j * 16 + (l & 15);
            bfr[j] = *(const bf16x8*)((const char*)Bs[cur] + row * 64 + kbyte);
        }
        __builtin_amdgcn_s_setprio(1);
#pragma unroll
        for (int i = 0; i < 4; ++i)
#pragma unroll
            for (int j = 0; j < 4; ++j)
                acc[i][j] = __builtin_amdgcn_mfma_f32_16x16x32_bf16(af[i], bfr[j], acc[i][j], 0, 0, 0);
        __builtin_amdgcn_s_setprio(0);
        __syncthreads();
    }

    // ---- epilogue ----
#pragma unroll
    for (int j = 0; j < 4; ++j) {
        int oc = o0 + wc + j * 16 + (l & 15);
        int h  = oc >> 6;
        int d  = oc & 63;
        float bv = bias[oc];
        if (mode == 2) {
#pragma unroll
            for (int rt = 0; rt < 4; ++rt) {
                int base = m0 + wr + rt * 16 + (l >> 4) * 4;
                int b_ = base >> 11, n0 = base & (NN - 1);
                u16 e[4];
#pragma unroll
                for (int r = 0; r < 4; ++r) e[r] = f2b(acc[rt][j][r] + bv);
                u32 lo = e[0] | ((u32)e[1] << 16);
                u32 hi = e[2] | ((u32)e[3] << 16);
                u16* vp = (u16*)out + (((size_t)b_ * NH + h) * HD + d) * NN + n0;
                *(uint2*)vp = uint2{lo, hi};
            }
        } else if (mode == 3) {
#pragma unroll
            for (int rt = 0; rt < 4; ++rt)
#pragma unroll
                for (int r = 0; r < 4; ++r) {
                    int m = m0 + wr + rt * 16 + (l >> 4) * 4 + r;
                    ((float*)out)[(size_t)m * HSZ + oc] = acc[rt][j][r] + bv;
                }
        } else {
            float scl = (mode == 0) ? QSCALE : 1.f;
#pragma unroll
            for (int rt = 0; rt < 4; ++rt)
#pragma unroll
                for (int r = 0; r < 4; ++r) {
                    int m = m0 + wr + rt * 16 + (l >> 4) * 4 + r;
                    int n = m & (NN - 1), b_ = m >> 11;
                    float v = acc[rt][j][r] + bv;
                    float2 cs = ((const float2*)tab)[n * 64 + d];
                    float part = __shfl_xor(v, 1);
                    float vr = (l & 1) ? fmaf(part, cs.y, v * cs.x)
                                       : fmaf(-part, cs.y, v * cs.x);
                    u16* qp = (u16*)out + (((size_t)b_ * NH + h) * NN + n) * HD + d;
                    *qp = f2b(vr * scl);
                }
        }
    }
}

__global__ __launch_bounds__(256)
void qkv_k(const u16* __restrict__ X,
           const u16* __restrict__ Wq, const u16* __restrict__ Wk, const u16* __restrict__ Wv,
           const float* __restrict__ bq, const float* __restrict__ bk, const float* __restrict__ bv,
           u16* __restrict__ qo, u16* __restrict__ ko, u16* __restrict__ vo,
           const float* __restrict__ tab) {
    int z = blockIdx.z;
    const u16* W   = (z == 0) ? Wq : (z == 1) ? Wk : Wv;
    const float* b = (z == 0) ? bq : (z == 1) ? bk : bv;
    u16* o         = (z == 0) ? qo : (z == 1) ? ko : vo;
    gemm_body(X, W, b, o, tab, z);
}

__global__ __launch_bounds__(256)
void projo_k(const u16* __restrict__ X, const u16* __restrict__ W,
             const float* __restrict__ b, float* __restrict__ out) {
    gemm_body(X, W, b, out, nullptr, 3);
}

// ---------------------------------------------------------------------------
// Swapped-QK^T flash attention (proven structure) with VALU diet:
//  - P pack via v_cvt_pk_bf16_f32; row-max via v_max3_f32 tree;
//  - l-sum via ones-MFMA (all lacc rows equal -> l = lacc[0], no shfl).
// KVBLK=64, QBLK=128, K/V dbuf 32KB, P in-register via permlane32_swap.
// ---------------------------------------------------------------------------
__global__ __launch_bounds__(256)
void attn_mfma_k(const u16* __restrict__ Qb, const u16* __restrict__ Kb,
                 const u16* __restrict__ Vtb, u16* __restrict__ ctxb) {
    __shared__ u16 KVs[2][2][64 * 64];   // [buf][0=K [kv][d], 1=V^T [d][kv]]

    const int t = threadIdx.x, w = t >> 6, l = t & 63;
    const int h = l >> 5;                // 32-lane half
    int f  = blockIdx.y * 16 + blockIdx.x;
    int bh = (f & 7) * 4 + ((f >> 3) & 3);   // 4 heads per XCD -> K/V L2-resident
    int qt = f >> 5;
    const int b_ = bh >> 4, hd = bh & 15;

    const u16* Qg = Qb + ((size_t)bh * NN + qt * 128) * HD;
    const u16* Kg = Kb + (size_t)bh * NN * HD;
    const u16* Vg = Vtb + (size_t)bh * HD * NN;

    const int xr   = (l & 7) << 4;
    const int h16  = h * 16;
    const int rowo = (l & 31) * 128;
    int kb4[4];
#pragma unroll
    for (int ks = 0; ks < 4; ++ks) kb4[ks] = ((ks * 32) | h16) ^ xr;

    const int ch  = w * 64 + l;
    const int r0  = ch >> 3,          sl0 = (ch & 7) ^ (r0 & 7);
    const int r1  = (ch + 256) >> 3,  sl1 = (ch & 7) ^ (r1 & 7);

    // ---- stage Q (16KB over KVs[0]) and hoist B-frags ----
#pragma unroll
    for (int s = 0; s < 4; ++s) {
        int c = s * 256 + ch;
        int row = c >> 3, sl = (c & 7) ^ (row & 7);
        gload16(&KVs[0][0][0] + (s * 256 + w * 64) * 8, Qg + row * HD + sl * 8);
    }
    __syncthreads();
    bf16x8 qf[4];
    {
        const char* Ql = (const char*)&KVs[0][0][0];
        int qrow = (w * 32 + (l & 31)) * 128;
#pragma unroll
        for (int ks = 0; ks < 4; ++ks)
            qf[ks] = *(const bf16x8*)(Ql + qrow + kb4[ks]);
    }
    __syncthreads();                     // all Q reads done before overwrite

    // ---- stage K/V tile 0 ----
    gload16(&KVs[0][0][0] + (w * 64) * 8,        Kg + (size_t)r0 * HD + sl0 * 8);
    gload16(&KVs[0][0][0] + (256 + w * 64) * 8,  Kg + (size_t)r1 * HD + sl1 * 8);
    gload16(&KVs[0][1][0] + (w * 64) * 8,        Vg + (size_t)r0 * NN + sl0 * 8);
    gload16(&KVs[0][1][0] + (256 + w * 64) * 8,  Vg + (size_t)r1 * NN + sl1 * 8);
    __syncthreads();

    bf16x8 ones;
#pragma unroll
    for (int i = 0; i < 8; ++i) ones[i] = (short)0x3F80;   // bf16 1.0

    float m_i = -INFINITY;
    f32x16 oa0 = {}, oa1 = {}, lacc = {};

    int cur = 0;
    for (int kt = 0; kt < NN / 64; ++kt, cur ^= 1) {
        if (kt + 1 < NN / 64) {          // prefetch next tile (drained at barrier)
            int nx = (kt + 1) * 64;
            gload16(&KVs[cur ^ 1][0][0] + (w * 64) * 8,       Kg + (size_t)(nx + r0) * HD + sl0 * 8);
            gload16(&KVs[cur ^ 1][0][0] + (256 + w * 64) * 8, Kg + (size_t)(nx + r1) * HD + sl1 * 8);
            gload16(&KVs[cur ^ 1][1][0] + (w * 64) * 8,       Vg + (size_t)r0 * NN + nx + sl0 * 8);
            gload16(&KVs[cur ^ 1][1][0] + (256 + w * 64) * 8, Vg + (size_t)r1 * NN + nx + sl1 * 8);
        }

        // ---- S^T = K Q^T : lane holds q=l&31, kv rows per reg ----
        const char* Kl = (const char*)&KVs[cur][0][0];
        f32x16 sa0 = {}, sa1 = {};
        __builtin_amdgcn_s_setprio(1);
#pragma unroll
        for (int ks = 0; ks < 4; ++ks) {
            bf16x8 k0 = *(const bf16x8*)(Kl + rowo + kb4[ks]);
            bf16x8 k1 = *(const bf16x8*)(Kl + 4096 + rowo + kb4[ks]);
            sa0 = __builtin_amdgcn_mfma_f32_32x32x16_bf16(k0, qf[ks], sa0, 0, 0, 0);
            sa1 = __builtin_amdgcn_mfma_f32_32x32x16_bf16(k1, qf[ks], sa1, 0, 0, 0);
        }
        __builtin_amdgcn_s_setprio(0);

        // ---- lane-local lazy max (v_max3 tree over 32 values) ----
        float a0 = max3(sa0[0], sa0[1], sa0[2]);
        float a1 = max3(sa0[3], sa0[4], sa0[5]);
        float a2 = max3(sa0[6], sa0[7], sa0[8]);
        float a3 = max3(sa0[9], sa0[10], sa0[11]);
        float a4 = max3(sa0[12], sa0[13], sa0[14]);
        float a5 = max3(sa1[0], sa1[1], sa1[2]);
        float a6 = max3(sa1[3], sa1[4], sa1[5]);
        float a7 = max3(sa1[6], sa1[7], sa1[8]);
        float a8 = max3(sa1[9], sa1[10], sa1[11]);
        float a9 = max3(sa1[12], sa1[13], sa1[14]);
        float aa = fmaxf(sa0[15], sa1[15]);
        float b0 = max3(a0, a1, a2);
        float b1 = max3(a3, a4, a5);
        float b2 = max3(a6, a7, a8);
        float b3 = max3(a9, aa, b0);
        float pmv = max3(b1, b2, b3);
        if (__any(pmv > m_i + DTHR)) {   // tile 0, then rare
            float mx = fmaxf(pmv, __shfl_xor(pmv, 32));
            float mn = fmaxf(m_i, mx);
            float alpha = __builtin_amdgcn_exp2f(m_i - mn);
            m_i = mn;
#pragma unroll
            for (int r = 0; r < 16; ++r) {
                oa0[r] *= alpha; oa1[r] *= alpha; lacc[r] *= alpha;
            }
        }

        // ---- P = exp2(S - m), packed cvt to bf16 pairs in-register ----
        u32 o_[16];
#pragma unroll
        for (int j = 0; j < 8; ++j) {
            float pa = __builtin_amdgcn_exp2f(sa0[2 * j]     - m_i);
            float pb = __builtin_amdgcn_exp2f(sa0[2 * j + 1] - m_i);
            float pc = __builtin_amdgcn_exp2f(sa1[2 * j]     - m_i);
            float pd = __builtin_amdgcn_exp2f(sa1[2 * j + 1] - m_i);
            o_[j]     = cvtpk(pa, pb);
            o_[8 + j] = cvtpk(pc, pd);
        }

        // ---- redistribute halves ----
        pswap(o_[0], o_[2]);   pswap(o_[1], o_[3]);
        pswap(o_[4], o_[6]);   pswap(o_[5], o_[7]);
        pswap(o_[8], o_[10]);  pswap(o_[9], o_[11]);
        pswap(o_[12], o_[14]); pswap(o_[13], o_[15]);

        // ---- O^T += V^T P^T ; l += 1^T P^T (ones-MFMA row sums) ----
        const char* Vl = (const char*)&KVs[cur][1][0];
        __builtin_amdgcn_s_setprio(1);
#pragma unroll
        for (int ks2 = 0; ks2 < 4; ++ks2) {
            union { u32 u[4]; bf16x8 v; } fr;
            fr.u[0] = o_[4 * ks2 + 0]; fr.u[1] = o_[4 * ks2 + 1];
            fr.u[2] = o_[4 * ks2 + 2]; fr.u[3] = o_[4 * ks2 + 3];
            bf16x8 v0 = *(const bf16x8*)(Vl + rowo + kb4[ks2]);
            bf16x8 v1 = *(const bf16x8*)(Vl + 4096 + rowo + kb4[ks2]);
            lacc = __builtin_amdgcn_mfma_f32_32x32x16_bf16(ones, fr.v, lacc, 0, 0, 0);
            oa0 = __builtin_amdgcn_mfma_f32_32x32x16_bf16(v0, fr.v, oa0, 0, 0, 0);
            oa1 = __builtin_amdgcn_mfma_f32_32x32x16_bf16(v1, fr.v, oa1, 0, 0, 0);
        }
        __builtin_amdgcn_s_setprio(0);

        __syncthreads();     // readers done with cur; prefetch (cur^1) drained
    }

    // ---- finalize: every lacc row equals l for this lane's q-col ----
    float inv = 1.f / lacc[0];
    int n = qt * 128 + w * 32 + (l & 31);
    u16* op = ctxb + ((size_t)b_ * NN + n) * HSZ + hd * 64;
#pragma unroll
    for (int dt = 0; dt < 2; ++dt) {
        const f32x16& oa = dt ? oa1 : oa0;
#pragma unroll
        for (int rg = 0; rg < 4; ++rg) {
            int d0 = 4 * h + 8 * rg + 32 * dt;
            u16 e0 = f2bc(oa[4 * rg + 0] * inv);
            u16 e1 = f2bc(oa[4 * rg + 1] * inv);
            u16 e2 = f2bc(oa[4 * rg + 2] * inv);
            u16 e3 = f2bc(oa[4 * rg + 3] * inv);
            *(uint2*)(op + d0) = uint2{e0 | ((u32)e1 << 16), e2 | ((u32)e3 << 16)};
        }
    }
}

// ---------------------------------------------------------------------------
extern "C" void kernel_launch(void* const* d_in, const int* in_sizes, int n_in,
                              void* d_out, int out_size, void* d_ws, size_t ws_size,
                              hipStream_t stream) {
    (void)in_sizes; (void)n_in; (void)out_size; (void)ws_size;
    const float* hs = (const float*)d_in[0];
    const float* Wq = (const float*)d_in[1];
    const float* bq = (const float*)d_in[2];
    const float* Wk = (const float*)d_in[3];
    const float* bk = (const float*)d_in[4];
    const float* Wv = (const float*)d_in[5];
    const float* bv = (const float*)d_in[6];
    const float* Wp = (const float*)d_in[7];
    const float* bp = (const float*)d_in[8];

    char* ws = (char*)d_ws;
    u16*   hsb  = (u16*)(ws);
    u16*   Wqb  = (u16*)(ws + 8388608);
    u16*   Wkb  = (u16*)(ws + 10485760);
    u16*   Wvb  = (u16*)(ws + 12582912);
    u16*   Wpb  = (u16*)(ws + 14680064);
    u16*   qb   = (u16*)(ws + 16777216);
    u16*   kb   = (u16*)(ws + 25165824);
    u16*   vtb  = (u16*)(ws + 33554432);
    u16*   ctxb = (u16*)(ws + 41943040);
    float* tab  = (float*)(ws + 50331648);

    cast_k<<<8192, 256, 0, stream>>>(hs, Wq, Wk, Wv, Wp, hsb, Wqb, Wkb, Wvb, Wpb);
    rope_table_k<<<NN, 64, 0, stream>>>(tab);

    qkv_k<<<dim3(HSZ / 128, (BB * NN) / 128, 3), 256, 0, stream>>>(
        hsb, Wqb, Wkb, Wvb, bq, bk, bv, qb, kb, vtb, tab);

    attn_mfma_k<<<dim3(NN / 128, BB * NH), 256, 0, stream>>>(qb, kb, vtb, ctxb);

    projo_k<<<dim3(HSZ / 128, (BB * NN) / 128), 256, 0, stream>>>(ctxb, Wpb, bp, (float*)d_out);
}

// Round 18
// 132.983 us; speedup vs baseline: 1.1148x; 1.0024x over previous
//
#include <hip/hip_runtime.h>
#include <hip/hip_bf16.h>
#include <math.h>

#define BB    2
#define NN    2048
#define HSZ   1024
#define NH    16
#define HD    64
#define SEGW  20

#define LOG2E  1.4426950408889634f
#define QSCALE (0.125f * LOG2E)     // folded into Q at projection time
#define DTHR   8.0f                 // defer-max threshold (log2 units)

typedef unsigned short u16;
typedef unsigned int   u32;
using bf16x8 = __attribute__((ext_vector_type(8))) short;
using f32x4  = __attribute__((ext_vector_type(4))) float;
using f32x16 = __attribute__((ext_vector_type(16))) float;

// float -> bf16 (RNE), manual
__device__ __forceinline__ u16 f2b(float f) {
    union { float f; u32 u; } x; x.f = f;
    u32 r = x.u + 0x7FFF + ((x.u >> 16) & 1);
    return (u16)(r >> 16);
}
// float -> bf16 via compiler cvt (hot path)
__device__ __forceinline__ u16 f2bc(float f) {
    __hip_bfloat16 h = __float2bfloat16(f);
    return *reinterpret_cast<u16*>(&h);
}
// packed 2x f32 -> bf16x2 in one instruction (lo -> low half)
__device__ __forceinline__ u32 cvtpk(float lo, float hi) {
    u32 r;
    asm("v_cvt_pk_bf16_f32 %0, %1, %2" : "=v"(r) : "v"(lo), "v"(hi));
    return r;
}
// 3-input max, single instruction
__device__ __forceinline__ float max3(float a, float b, float c) {
    float d;
    asm("v_max3_f32 %0, %1, %2, %3" : "=v"(d) : "v"(a), "v"(b), "v"(c));
    return d;
}

// async global->LDS, 16B/lane; lds base wave-uniform
__device__ __forceinline__ void gload16(void* lds, const void* g) {
    __builtin_amdgcn_global_load_lds(
        (const __attribute__((address_space(1))) void*)g,
        (__attribute__((address_space(3))) void*)lds, 16, 0, 0);
}

// v_permlane32_swap_b32: a.row1 <-> b.row0  (rows = 32-lane halves)
__device__ __forceinline__ void pswap(u32& a, u32& b) {
    asm volatile("v_permlane32_swap_b32 %0, %1" : "+v"(a), "+v"(b));
}

// ---------------------------------------------------------------------------
__global__ __launch_bounds__(256)
void cast_k(const float* __restrict__ hs, const float* __restrict__ Wq,
            const float* __restrict__ Wk, const float* __restrict__ Wv,
            const float* __restrict__ Wp, u16* __restrict__ hsb,
            u16* __restrict__ wqb, u16* __restrict__ wkb,
            u16* __restrict__ wvb, u16* __restrict__ wpb) {
    size_t idx = ((size_t)blockIdx.x * 256 + threadIdx.x) * 4;
    const float* s; u16* d; size_t o;
    const size_t HSN = 4194304, WN = 1048576;
    if      (idx < HSN)          { s = hs; d = hsb; o = idx; }
    else if (idx < HSN + WN)     { s = Wq; d = wqb; o = idx - HSN; }
    else if (idx < HSN + 2*WN)   { s = Wk; d = wkb; o = idx - HSN - WN; }
    else if (idx < HSN + 3*WN)   { s = Wv; d = wvb; o = idx - HSN - 2*WN; }
    else                         { s = Wp; d = wpb; o = idx - HSN - 3*WN; }
    float4 v = *(const float4*)(s + o);
    u32 lo = f2b(v.x) | ((u32)f2b(v.y) << 16);
    u32 hi = f2b(v.z) | ((u32)f2b(v.w) << 16);
    *(uint2*)(d + o) = uint2{lo, hi};
}

// ---------------------------------------------------------------------------
__global__ void rope_table_k(float* __restrict__ tab) {
    int n = blockIdx.x, d = threadIdx.x;
    float c = 1.f, s = 0.f;
    if (d < 3 * SEGW) {
        int seg = d / SEGW;
        int jj  = (d % SEGW) % (SEGW / 2);
        int rem = n & 255;
        int pos = (seg == 0) ? (n >> 8) : ((seg == 1) ? (rem >> 4) : (rem & 15));
        float omega = powf(10000.f, -(float)jj / 10.f);
        float fr = (float)pos * omega;
        s = sinf(fr); c = cosf(fr);
    }
    tab[(n * 64 + d) * 2 + 0] = c;
    tab[(n * 64 + d) * 2 + 1] = s;
}

// ---------------------------------------------------------------------------
// The proven GEMM: BM=BN=128, BK=32, A AND B both via global_load_lds
// dbuf (32KB LDS), 1 barrier/iter, staging source pre-swizzled by
// (c&3)^(row&3), XCD-locality remap (flat = bx + by*8).
// mode 0: rope+QSCALE bf16 [bh][n][d]; 1: rope bf16; 2: bf16 [bh][d][n] (V^T);
// mode 3: fp32 [m][o].
// ---------------------------------------------------------------------------
__device__ __forceinline__
void gemm_body(const u16* __restrict__ X, const u16* __restrict__ Wb,
               const float* __restrict__ bias, void* __restrict__ out,
               const float* __restrict__ tab, int mode) {
    __shared__ u16 As[2][128 * 32];
    __shared__ u16 Bs[2][128 * 32];

    const int t  = threadIdx.x;
    const int w  = t >> 6;
    const int l  = t & 63;
    const int flat = blockIdx.x + (blockIdx.y << 3);
    const int o0 = (flat >> 5) * 128;
    const int m0 = (flat & 31) * 128;
    const int wr = (w >> 1) * 64;
    const int wc = (w & 1) * 64;

    const int ch  = (w << 6) + l;
    const int rA0 = ch >> 2,         cA0 = (((ch & 3) ^ (rA0 & 3))) * 8;
    const int rA1 = (ch + 256) >> 2, cA1 = (((ch & 3) ^ (rA1 & 3))) * 8;
    const int kbyte = (((l >> 4) ^ (l & 3)) << 4);

    f32x4 acc[4][4] = {};

    gload16(As[0] + ((w << 6)) * 8,       X  + (size_t)(m0 + rA0) * HSZ + cA0);
    gload16(As[0] + (256 + (w << 6)) * 8, X  + (size_t)(m0 + rA1) * HSZ + cA1);
    gload16(Bs[0] + ((w << 6)) * 8,       Wb + (size_t)(o0 + rA0) * HSZ + cA0);
    gload16(Bs[0] + (256 + (w << 6)) * 8, Wb + (size_t)(o0 + rA1) * HSZ + cA1);
    __syncthreads();

    int cur = 0;
    for (int k0 = 0; k0 < HSZ; k0 += 32, cur ^= 1) {
        if (k0 + 32 < HSZ) {
            int kn = k0 + 32;
            gload16(As[cur ^ 1] + ((w << 6)) * 8,       X  + (size_t)(m0 + rA0) * HSZ + kn + cA0);
            gload16(As[cur ^ 1] + (256 + (w << 6)) * 8, X  + (size_t)(m0 + rA1) * HSZ + kn + cA1);
            gload16(Bs[cur ^ 1] + ((w << 6)) * 8,       Wb + (size_t)(o0 + rA0) * HSZ + kn + cA0);
            gload16(Bs[cur ^ 1] + (256 + (w << 6)) * 8, Wb + (size_t)(o0 + rA1) * HSZ + kn + cA1);
        }
        bf16x8 af[4], bfr[4];
#pragma unroll
        for (int i = 0; i < 4; ++i) {
            int row = wr + i * 16 + (l & 15);
            af[i] = *(const bf16x8*)((const char*)As[cur] + row * 64 + kbyte);
        }
#pragma unroll
        for (int j = 0; j < 4; ++j) {
            int row = wc + j * 16 + (l & 15);
            bfr[j] = *(const bf16x8*)((const char*)Bs[cur] + row * 64 + kbyte);
        }
        __builtin_amdgcn_s_setprio(1);
#pragma unroll
        for (int i = 0; i < 4; ++i)
#pragma unroll
            for (int j = 0; j < 4; ++j)
                acc[i][j] = __builtin_amdgcn_mfma_f32_16x16x32_bf16(af[i], bfr[j], acc[i][j], 0, 0, 0);
        __builtin_amdgcn_s_setprio(0);
        __syncthreads();
    }

    // ---- epilogue ----
#pragma unroll
    for (int j = 0; j < 4; ++j) {
        int oc = o0 + wc + j * 16 + (l & 15);
        int h  = oc >> 6;
        int d  = oc & 63;
        float bv = bias[oc];
        if (mode == 2) {
#pragma unroll
            for (int rt = 0; rt < 4; ++rt) {
                int base = m0 + wr + rt * 16 + (l >> 4) * 4;
                int b_ = base >> 11, n0 = base & (NN - 1);
                u16 e[4];
#pragma unroll
                for (int r = 0; r < 4; ++r) e[r] = f2b(acc[rt][j][r] + bv);
                u32 lo = e[0] | ((u32)e[1] << 16);
                u32 hi = e[2] | ((u32)e[3] << 16);
                u16* vp = (u16*)out + (((size_t)b_ * NH + h) * HD + d) * NN + n0;
                *(uint2*)vp = uint2{lo, hi};
            }
        } else if (mode == 3) {
#pragma unroll
            for (int rt = 0; rt < 4; ++rt)
#pragma unroll
                for (int r = 0; r < 4; ++r) {
                    int m = m0 + wr + rt * 16 + (l >> 4) * 4 + r;
                    ((float*)out)[(size_t)m * HSZ + oc] = acc[rt][j][r] + bv;
                }
        } else {
            float scl = (mode == 0) ? QSCALE : 1.f;
#pragma unroll
            for (int rt = 0; rt < 4; ++rt)
#pragma unroll
                for (int r = 0; r < 4; ++r) {
                    int m = m0 + wr + rt * 16 + (l >> 4) * 4 + r;
                    int n = m & (NN - 1), b_ = m >> 11;
                    float v = acc[rt][j][r] + bv;
                    float2 cs = ((const float2*)tab)[n * 64 + d];
                    float part = __shfl_xor(v, 1);
                    float vr = (l & 1) ? fmaf(part, cs.y, v * cs.x)
                                       : fmaf(-part, cs.y, v * cs.x);
                    u16* qp = (u16*)out + (((size_t)b_ * NH + h) * NN + n) * HD + d;
                    *qp = f2b(vr * scl);
                }
        }
    }
}

__global__ __launch_bounds__(256)
void qkv_k(const u16* __restrict__ X,
           const u16* __restrict__ Wq, const u16* __restrict__ Wk, const u16* __restrict__ Wv,
           const float* __restrict__ bq, const float* __restrict__ bk, const float* __restrict__ bv,
           u16* __restrict__ qo, u16* __restrict__ ko, u16* __restrict__ vo,
           const float* __restrict__ tab) {
    int z = blockIdx.z;
    const u16* W   = (z == 0) ? Wq : (z == 1) ? Wk : Wv;
    const float* b = (z == 0) ? bq : (z == 1) ? bk : bv;
    u16* o         = (z == 0) ? qo : (z == 1) ? ko : vo;
    gemm_body(X, W, b, o, tab, z);
}

__global__ __launch_bounds__(256)
void projo_k(const u16* __restrict__ X, const u16* __restrict__ W,
             const float* __restrict__ b, float* __restrict__ out) {
    gemm_body(X, W, b, out, nullptr, 3);
}

// ---------------------------------------------------------------------------
// Swapped-QK^T flash attention (proven structure) with VALU diet:
//  - P pack via v_cvt_pk_bf16_f32; row-max via v_max3_f32 tree;
//  - l-sum via ones-MFMA (all lacc rows equal -> l = lacc[0], no shfl).
// KVBLK=64, QBLK=128, K/V dbuf 32KB, P in-register via permlane32_swap.
// ---------------------------------------------------------------------------
__global__ __launch_bounds__(256)
void attn_mfma_k(const u16* __restrict__ Qb, const u16* __restrict__ Kb,
                 const u16* __restrict__ Vtb, u16* __restrict__ ctxb) {
    __shared__ u16 KVs[2][2][64 * 64];   // [buf][0=K [kv][d], 1=V^T [d][kv]]

    const int t = threadIdx.x, w = t >> 6, l = t & 63;
    const int h = l >> 5;                // 32-lane half
    int f  = blockIdx.y * 16 + blockIdx.x;
    int bh = (f & 7) * 4 + ((f >> 3) & 3);   // 4 heads per XCD -> K/V L2-resident
    int qt = f >> 5;
    const int b_ = bh >> 4, hd = bh & 15;

    const u16* Qg = Qb + ((size_t)bh * NN + qt * 128) * HD;
    const u16* Kg = Kb + (size_t)bh * NN * HD;
    const u16* Vg = Vtb + (size_t)bh * HD * NN;

    const int xr   = (l & 7) << 4;
    const int h16  = h * 16;
    const int rowo = (l & 31) * 128;
    int kb4[4];
#pragma unroll
    for (int ks = 0; ks < 4; ++ks) kb4[ks] = ((ks * 32) | h16) ^ xr;

    const int ch  = w * 64 + l;
    const int r0  = ch >> 3,          sl0 = (ch & 7) ^ (r0 & 7);
    const int r1  = (ch + 256) >> 3,  sl1 = (ch & 7) ^ (r1 & 7);

    // ---- stage Q (16KB over KVs[0]) and hoist B-frags ----
#pragma unroll
    for (int s = 0; s < 4; ++s) {
        int c = s * 256 + ch;
        int row = c >> 3, sl = (c & 7) ^ (row & 7);
        gload16(&KVs[0][0][0] + (s * 256 + w * 64) * 8, Qg + row * HD + sl * 8);
    }
    __syncthreads();
    bf16x8 qf[4];
    {
        const char* Ql = (const char*)&KVs[0][0][0];
        int qrow = (w * 32 + (l & 31)) * 128;
#pragma unroll
        for (int ks = 0; ks < 4; ++ks)
            qf[ks] = *(const bf16x8*)(Ql + qrow + kb4[ks]);
    }
    __syncthreads();                     // all Q reads done before overwrite

    // ---- stage K/V tile 0 ----
    gload16(&KVs[0][0][0] + (w * 64) * 8,        Kg + (size_t)r0 * HD + sl0 * 8);
    gload16(&KVs[0][0][0] + (256 + w * 64) * 8,  Kg + (size_t)r1 * HD + sl1 * 8);
    gload16(&KVs[0][1][0] + (w * 64) * 8,        Vg + (size_t)r0 * NN + sl0 * 8);
    gload16(&KVs[0][1][0] + (256 + w * 64) * 8,  Vg + (size_t)r1 * NN + sl1 * 8);
    __syncthreads();

    bf16x8 ones;
#pragma unroll
    for (int i = 0; i < 8; ++i) ones[i] = (short)0x3F80;   // bf16 1.0

    float m_i = -INFINITY;
    f32x16 oa0 = {}, oa1 = {}, lacc = {};

    int cur = 0;
    for (int kt = 0; kt < NN / 64; ++kt, cur ^= 1) {
        if (kt + 1 < NN / 64) {          // prefetch next tile (drained at barrier)
            int nx = (kt + 1) * 64;
            gload16(&KVs[cur ^ 1][0][0] + (w * 64) * 8,       Kg + (size_t)(nx + r0) * HD + sl0 * 8);
            gload16(&KVs[cur ^ 1][0][0] + (256 + w * 64) * 8, Kg + (size_t)(nx + r1) * HD + sl1 * 8);
            gload16(&KVs[cur ^ 1][1][0] + (w * 64) * 8,       Vg + (size_t)r0 * NN + nx + sl0 * 8);
            gload16(&KVs[cur ^ 1][1][0] + (256 + w * 64) * 8, Vg + (size_t)r1 * NN + nx + sl1 * 8);
        }

        // ---- S^T = K Q^T : lane holds q=l&31, kv rows per reg ----
        const char* Kl = (const char*)&KVs[cur][0][0];
        f32x16 sa0 = {}, sa1 = {};
        __builtin_amdgcn_s_setprio(1);
#pragma unroll
        for (int ks = 0; ks < 4; ++ks) {
            bf16x8 k0 = *(const bf16x8*)(Kl + rowo + kb4[ks]);
            bf16x8 k1 = *(const bf16x8*)(Kl + 4096 + rowo + kb4[ks]);
            sa0 = __builtin_amdgcn_mfma_f32_32x32x16_bf16(k0, qf[ks], sa0, 0, 0, 0);
            sa1 = __builtin_amdgcn_mfma_f32_32x32x16_bf16(k1, qf[ks], sa1, 0, 0, 0);
        }
        __builtin_amdgcn_s_setprio(0);

        // ---- lane-local lazy max (v_max3 tree over 32 values) ----
        float a0 = max3(sa0[0], sa0[1], sa0[2]);
        float a1 = max3(sa0[3], sa0[4], sa0[5]);
        float a2 = max3(sa0[6], sa0[7], sa0[8]);
        float a3 = max3(sa0[9], sa0[10], sa0[11]);
        float a4 = max3(sa0[12], sa0[13], sa0[14]);
        float a5 = max3(sa1[0], sa1[1], sa1[2]);
        float a6 = max3(sa1[3], sa1[4], sa1[5]);
        float a7 = max3(sa1[6], sa1[7], sa1[8]);
        float a8 = max3(sa1[9], sa1[10], sa1[11]);
        float a9 = max3(sa1[12], sa1[13], sa1[14]);
        float aa = fmaxf(sa0[15], sa1[15]);
        float b0 = max3(a0, a1, a2);
        float b1 = max3(a3, a4, a5);
        float b2 = max3(a6, a7, a8);
        float b3 = max3(a9, aa, b0);
        float pmv = max3(b1, b2, b3);
        if (__any(pmv > m_i + DTHR)) {   // tile 0, then rare
            float mx = fmaxf(pmv, __shfl_xor(pmv, 32));
            float mn = fmaxf(m_i, mx);
            float alpha = __builtin_amdgcn_exp2f(m_i - mn);
            m_i = mn;
#pragma unroll
            for (int r = 0; r < 16; ++r) {
                oa0[r] *= alpha; oa1[r] *= alpha; lacc[r] *= alpha;
            }
        }

        // ---- P = exp2(S - m), packed cvt to bf16 pairs in-register ----
        u32 o_[16];
#pragma unroll
        for (int j = 0; j < 8; ++j) {
            float pa = __builtin_amdgcn_exp2f(sa0[2 * j]     - m_i);
            float pb = __builtin_amdgcn_exp2f(sa0[2 * j + 1] - m_i);
            float pc = __builtin_amdgcn_exp2f(sa1[2 * j]     - m_i);
            float pd = __builtin_amdgcn_exp2f(sa1[2 * j + 1] - m_i);
            o_[j]     = cvtpk(pa, pb);
            o_[8 + j] = cvtpk(pc, pd);
        }

        // ---- redistribute halves ----
        pswap(o_[0], o_[2]);   pswap(o_[1], o_[3]);
        pswap(o_[4], o_[6]);   pswap(o_[5], o_[7]);
        pswap(o_[8], o_[10]);  pswap(o_[9], o_[11]);
        pswap(o_[12], o_[14]); pswap(o_[13], o_[15]);

        // ---- O^T += V^T P^T ; l += 1^T P^T (ones-MFMA row sums) ----
        const char* Vl = (const char*)&KVs[cur][1][0];
        __builtin_amdgcn_s_setprio(1);
#pragma unroll
        for (int ks2 = 0; ks2 < 4; ++ks2) {
            union { u32 u[4]; bf16x8 v; } fr;
            fr.u[0] = o_[4 * ks2 + 0]; fr.u[1] = o_[4 * ks2 + 1];
            fr.u[2] = o_[4 * ks2 + 2]; fr.u[3] = o_[4 * ks2 + 3];
            bf16x8 v0 = *(const bf16x8*)(Vl + rowo + kb4[ks2]);
            bf16x8 v1 = *(const bf16x8*)(Vl + 4096 + rowo + kb4[ks2]);
            lacc = __builtin_amdgcn_mfma_f32_32x32x16_bf16(ones, fr.v, lacc, 0, 0, 0);
            oa0 = __builtin_amdgcn_mfma_f32_32x32x16_bf16(v0, fr.v, oa0, 0, 0, 0);
            oa1 = __builtin_amdgcn_mfma_f32_32x32x16_bf16(v1, fr.v, oa1, 0, 0, 0);
        }
        __builtin_amdgcn_s_setprio(0);

        __syncthreads();     // readers done with cur; prefetch (cur^1) drained
    }

    // ---- finalize: every lacc row equals l for this lane's q-col ----
    float inv = 1.f / lacc[0];
    int n = qt * 128 + w * 32 + (l & 31);
    u16* op = ctxb + ((size_t)b_ * NN + n) * HSZ + hd * 64;
#pragma unroll
    for (int dt = 0; dt < 2; ++dt) {
        const f32x16& oa = dt ? oa1 : oa0;
#pragma unroll
        for (int rg = 0; rg < 4; ++rg) {
            int d0 = 4 * h + 8 * rg + 32 * dt;
            u16 e0 = f2bc(oa[4 * rg + 0] * inv);
            u16 e1 = f2bc(oa[4 * rg + 1] * inv);
            u16 e2 = f2bc(oa[4 * rg + 2] * inv);
            u16 e3 = f2bc(oa[4 * rg + 3] * inv);
            *(uint2*)(op + d0) = uint2{e0 | ((u32)e1 << 16), e2 | ((u32)e3 << 16)};
        }
    }
}

// ---------------------------------------------------------------------------
extern "C" void kernel_launch(void* const* d_in, const int* in_sizes, int n_in,
                              void* d_out, int out_size, void* d_ws, size_t ws_size,
                              hipStream_t stream) {
    (void)in_sizes; (void)n_in; (void)out_size; (void)ws_size;
    const float* hs = (const float*)d_in[0];
    const float* Wq = (const float*)d_in[1];
    const float* bq = (const float*)d_in[2];
    const float* Wk = (const float*)d_in[3];
    const float* bk = (const float*)d_in[4];
    const float* Wv = (const float*)d_in[5];
    const float* bv = (const float*)d_in[6];
    const float* Wp = (const float*)d_in[7];
    const float* bp = (const float*)d_in[8];

    char* ws = (char*)d_ws;
    u16*   hsb  = (u16*)(ws);
    u16*   Wqb  = (u16*)(ws + 8388608);
    u16*   Wkb  = (u16*)(ws + 10485760);
    u16*   Wvb  = (u16*)(ws + 12582912);
    u16*   Wpb  = (u16*)(ws + 14680064);
    u16*   qb   = (u16*)(ws + 16777216);
    u16*   kb   = (u16*)(ws + 25165824);
    u16*   vtb  = (u16*)(ws + 33554432);
    u16*   ctxb = (u16*)(ws + 41943040);
    float* tab  = (float*)(ws + 50331648);

    cast_k<<<8192, 256, 0, stream>>>(hs, Wq, Wk, Wv, Wp, hsb, Wqb, Wkb, Wvb, Wpb);
    rope_table_k<<<NN, 64, 0, stream>>>(tab);

    qkv_k<<<dim3(HSZ / 128, (BB * NN) / 128, 3), 256, 0, stream>>>(
        hsb, Wqb, Wkb, Wvb, bq, bk, bv, qb, kb, vtb, tab);

    attn_mfma_k<<<dim3(NN / 128, BB * NH), 256, 0, stream>>>(qb, kb, vtb, ctxb);

    projo_k<<<dim3(HSZ / 128, (BB * NN) / 128), 256, 0, stream>>>(ctxb, Wpb, bp, (float*)d_out);
}